// Round 6
// baseline (49.724 us; speedup 1.0000x reference)
//
#include <hip/hip_runtime.h>

typedef int int4v __attribute__((ext_vector_type(4)));

// Problem constants
#define IN_C    64
#define OUT_C   128
#define KTOT    576
#define N_W     73728       // 128*3*3*64
#define N_OUT   25690112

// Halo tiling: 8x8 output pixels per tile, 10x10 halo, double-buffered LDS.
#define PIXB    80          // bytes per halo pixel slot (64 data + 16 pad)
#define NTILES  3136        // 64 images x 7x7 tiles
#define NBLK    512         // persistent blocks; 2 per CU

// ---------------------------------------------------------------------------
// Pack weights into fragment order for mfma_i32_16x16x64_i8 (vectorized).
//   dest byte t = ((kt*8 + nt)*64 + lane)*16 + byte
//   holds W[k][n], k = kt*64 + (lane>>4)*16 + byte, n = nt*16 + (lane&15)
__global__ __launch_bounds__(256) void pack_w_kernel(const int* __restrict__ wgt,
                                                     unsigned int* __restrict__ w8) {
    int t = blockIdx.x * 256 + threadIdx.x;   // t < 18432
    int d = t << 2;
    int byte = d & 15;
    int lane = (d >> 4) & 63;
    int ntk  = d >> 10;
    int nt   = ntk & 7;
    int kt   = ntk >> 3;
    int k = kt * 64 + ((lane >> 4) << 4) + byte;
    int n = nt * 16 + (lane & 15);
    int4v v = *(const int4v*)(wgt + n * KTOT + k);
    w8[t] = (v.x & 0xff) | ((v.y & 0xff) << 8) | ((v.z & 0xff) << 16)
          | ((unsigned int)v.w << 24);
}

__device__ __forceinline__ int pack4(int4v a) {
    return (a.x & 0xff) | ((a.y & 0xff) << 8) | ((a.z & 0xff) << 16) | (a.w << 24);
}

// ---------------------------------------------------------------------------
// Persistent 2-phase pipelined halo conv. Block = 6-7 contiguous 8x8 tiles.
// Per tile: A = weights (M=channels), B = x pixels (N=pixels); D row=channel.
__global__ __launch_bounds__(256, 2) void conv_pipe_kernel(const int* __restrict__ x32,
                                                           const char* __restrict__ w8,
                                                           const int* __restrict__ bias,
                                                           int* __restrict__ out) {
    __shared__ char hx[2][100 * PIXB];

    const int tid  = threadIdx.x;
    const int lane = tid & 63;
    const int wv   = tid >> 6;
    const int l15  = lane & 15;
    const int l4   = lane >> 4;

    // XCD-chunked bijective block->range map: rb in [0,512); XCD x owns
    // rb in [x*64,(x+1)*64) -> tiles [x*392,(x+1)*392) = 8 whole images.
    const int rb = ((blockIdx.x & 7) << 6) + (blockIdx.x >> 3);
    const int t0 = (rb * NTILES) >> 9;            // floor(rb * 6.125)
    const int t1 = ((rb + 1) * NTILES) >> 9;

    // Staging geometry: 400 units of (64B int32 -> 16B int8); unit0 = tid,
    // unit1 = tid+256 (threads 0..143 only).
    const int pix0 = tid >> 2, q0 = tid & 3;
    const int hr0 = pix0 / 10, hc0 = pix0 - hr0 * 10;
    const bool has1 = tid < 144;
    const int pix1 = (tid + 256) >> 2, q1 = tid & 3;   // (tid+256)&3 == tid&3
    const int hr1 = pix1 / 10, hc1 = pix1 - hr1 * 10;

    // Per-lane constants.
    const int lanebase = ((l15 >> 3) * 10 + (l15 & 7)) * PIXB + (l4 << 4);
    const int chb = wv * 32 + (l4 << 2);
    const int4v bv0 = *(const int4v*)(bias + chb);
    const int4v bv1 = *(const int4v*)(bias + chb + 16);
    const int pc = l15 & 7, prl = l15 >> 3;
    const char* wbase = w8 + (((wv * 2) * 64 + lane) << 4);

    int4v r00, r01, r02, r03, r10, r11, r12, r13;
    bool ok0 = false, ok1 = false;

    auto load_tile = [&](int t) {
        int n  = t / 49;
        int rr = t - n * 49;
        int th = rr / 7, tw = rr - th * 7;
        int h0 = th * 8 - 1, w0 = tw * 8 - 1;
        int gh0 = h0 + hr0, gw0 = w0 + hc0;
        ok0 = ((unsigned)gh0 < 56u) & ((unsigned)gw0 < 56u);
        if (ok0) {
            const int4v* s = (const int4v*)x32 + (((n * 56 + gh0) * 56 + gw0) << 4) + (q0 << 2);
            r00 = s[0]; r01 = s[1]; r02 = s[2]; r03 = s[3];
        }
        if (has1) {
            int gh1 = h0 + hr1, gw1 = w0 + hc1;
            ok1 = ((unsigned)gh1 < 56u) & ((unsigned)gw1 < 56u);
            if (ok1) {
                const int4v* s = (const int4v*)x32 + (((n * 56 + gh1) * 56 + gw1) << 4) + (q1 << 2);
                r10 = s[0]; r11 = s[1]; r12 = s[2]; r13 = s[3];
            }
        }
    };

    auto write_tile = [&](int buf) {
        int4v pk = {0, 0, 0, 0};
        if (ok0) { pk.x = pack4(r00); pk.y = pack4(r01); pk.z = pack4(r02); pk.w = pack4(r03); }
        *(int4v*)(hx[buf] + pix0 * PIXB + (q0 << 4)) = pk;
        if (has1) {
            int4v pk1 = {0, 0, 0, 0};
            if (ok1) { pk1.x = pack4(r10); pk1.y = pack4(r11); pk1.z = pack4(r12); pk1.w = pack4(r13); }
            *(int4v*)(hx[buf] + pix1 * PIXB + (q1 << 4)) = pk1;
        }
    };

    // ---- Prologue: stage first tile.
    load_tile(t0);
    write_tile(0);

    int cur = 0;
#pragma unroll 1
    for (int t = t0; t < t1; ++t) {
        const bool hn = (t + 1) < t1;
        if (hn) load_tile(t + 1);             // issue next tile's loads early
        __syncthreads();                      // buf[cur] ready

        // ---- Compute tile t from hx[cur].
        int n  = t / 49;
        int rr = t - n * 49;
        int th = rr / 7, tw = rr - th * 7;
        const char* ap = hx[cur] + lanebase;

        int4v acc[4][2];
#pragma unroll
        for (int mt = 0; mt < 4; ++mt) {
            acc[mt][0] = (int4v){0, 0, 0, 0};
            acc[mt][1] = (int4v){0, 0, 0, 0};
        }

        const char* wp = wbase;
        int4v bc0 = *(const int4v*)(wp);
        int4v bc1 = *(const int4v*)(wp + 1024);
        int toff = 0;
#pragma unroll 1
        for (int kt = 0; kt < 9; ++kt) {
            wp += 8192;
            int4v bn0 = *(const int4v*)(wp);      // kt=8 load hits scratch tail
            int4v bn1 = *(const int4v*)(wp + 1024);
#pragma unroll
            for (int mt = 0; mt < 4; ++mt) {
                int4v a = *(const int4v*)(ap + toff + mt * 1600);
                acc[mt][0] = __builtin_amdgcn_mfma_i32_16x16x64_i8(bc0, a, acc[mt][0], 0, 0, 0);
                acc[mt][1] = __builtin_amdgcn_mfma_i32_16x16x64_i8(bc1, a, acc[mt][1], 0, 0, 0);
            }
            bc0 = bn0;
            bc1 = bn1;
            toff += 80;
            if ((kt == 2) | (kt == 5)) toff += 560;
        }

        // ---- Epilogue: lane holds 4 consecutive channels -> dwordx4 stores.
        int* ob = out + (((n * 56 + th * 8) * 56 + tw * 8) << 7);
#pragma unroll
        for (int mt = 0; mt < 4; ++mt) {
            int pr = (mt << 1) + prl;
            int* o = ob + ((pr * 56 + pc) << 7) + chb;
            *(int4v*)(o)      = acc[mt][0] + bv0;
            *(int4v*)(o + 16) = acc[mt][1] + bv1;
        }

        // ---- Stage next tile into the other buffer.
        if (hn) write_tile(cur ^ 1);
        cur ^= 1;
    }
}

// ---------------------------------------------------------------------------
// Fallback (only if workspace is too small): direct conv, 1 thread/output.
__global__ __launch_bounds__(256) void conv_naive_kernel(const int* __restrict__ x,
                                                         const int* __restrict__ wgt,
                                                         const int* __restrict__ bias,
                                                         int* __restrict__ out) {
    int idx = blockIdx.x * 256 + threadIdx.x;
    if (idx >= N_OUT) return;
    int ch  = idx & 127;
    int pix = idx >> 7;
    int n  = pix / 3136;
    int r2 = pix - n * 3136;
    int h  = r2 / 56;
    int w  = r2 - h * 56;
    int acc = bias[ch];
    for (int kh = 0; kh < 3; ++kh) {
        int hxr = h + kh - 1;
        if ((unsigned)hxr >= 56u) continue;
        for (int kw = 0; kw < 3; ++kw) {
            int wx = w + kw - 1;
            if ((unsigned)wx >= 56u) continue;
            const int* xp = x + ((n * 56 + hxr) * 56 + wx) * 64;
            const int* wp = wgt + ch * KTOT + (kh * 3 + kw) * 64;
            for (int ic = 0; ic < 64; ++ic) acc += xp[ic] * wp[ic];
        }
    }
    out[idx] = acc;
}

// ---------------------------------------------------------------------------
extern "C" void kernel_launch(void* const* d_in, const int* in_sizes, int n_in,
                              void* d_out, int out_size, void* d_ws, size_t ws_size,
                              hipStream_t stream) {
    const int* x    = (const int*)d_in[0];
    const int* wgt  = (const int*)d_in[1];
    const int* bias = (const int*)d_in[2];
    int* out = (int*)d_out;

    if (ws_size >= (size_t)(N_W + 8192)) {
        char* w8 = (char*)d_ws;              // N_W bytes + 8KB prefetch tail
        pack_w_kernel<<<N_W / 4 / 256, 256, 0, stream>>>(wgt, (unsigned int*)w8);
        conv_pipe_kernel<<<NBLK, 256, 0, stream>>>(x, w8, bias, out);
    } else {
        conv_naive_kernel<<<(N_OUT + 255) / 256, 256, 0, stream>>>(x, wgt, bias, out);
    }
}

// Round 7
// 39.917 us; speedup vs baseline: 1.2457x; 1.2457x over previous
//
#include <hip/hip_runtime.h>

typedef int int4v __attribute__((ext_vector_type(4)));

// Problem constants
#define IN_C    64
#define OUT_C   128
#define KTOT    576
#define N_W     73728       // 128*3*3*64
#define N_OUT   25690112

// Halo tiling: 8x8 output pixels per block, 10x10 halo in LDS.
#define PIXB    80          // bytes per halo pixel slot (64 data + 16 pad)
#define NTILES  3136        // 64 images x 7x7 tiles

// ---------------------------------------------------------------------------
// Pack weights into fragment order for mfma_i32_16x16x64_i8 (vectorized).
//   dest byte t = ((kt*8 + nt)*64 + lane)*16 + byte
//   holds W[k][n], k = kt*64 + (lane>>4)*16 + byte, n = nt*16 + (lane&15)
__global__ __launch_bounds__(256) void pack_w_kernel(const int* __restrict__ wgt,
                                                     unsigned int* __restrict__ w8) {
    int t = blockIdx.x * 256 + threadIdx.x;   // t < 18432
    int d = t << 2;
    int byte = d & 15;
    int lane = (d >> 4) & 63;
    int ntk  = d >> 10;
    int nt   = ntk & 7;
    int kt   = ntk >> 3;
    int k = kt * 64 + ((lane >> 4) << 4) + byte;
    int n = nt * 16 + (lane & 15);
    int4v v = *(const int4v*)(wgt + n * KTOT + k);
    w8[t] = (v.x & 0xff) | ((v.y & 0xff) << 8) | ((v.z & 0xff) << 16)
          | ((unsigned int)v.w << 24);
}

__device__ __forceinline__ int pack4(int4v a) {
    return (a.x & 0xff) | ((a.y & 0xff) << 8) | ((a.z & 0xff) << 16) | (a.w << 24);
}

// ---------------------------------------------------------------------------
// Halo-tile MFMA conv (round-5 structure + depth-4 weight prefetch).
// Block = 8x8 pixels x 128 channels, 4 waves. A = weights (M=channels),
// B = x pixels (N=pixels) -> D row = channel -> dwordx4 epilogue stores.
__global__ __launch_bounds__(256, 4) void conv_halo_kernel(const int* __restrict__ x32,
                                                           const char* __restrict__ w8,
                                                           const int* __restrict__ bias,
                                                           int* __restrict__ out) {
    __shared__ char hx[100 * PIXB];

    const int tid  = threadIdx.x;
    const int lane = tid & 63;
    const int wv   = tid >> 6;
    const int l15  = lane & 15;
    const int l4   = lane >> 4;

    // XCD-chunked bijective swizzle: grid 3136 = 8 XCDs x 392 (8 whole images).
    const int bid = blockIdx.x;
    const int nb  = (bid & 7) * 392 + (bid >> 3);

    const int n   = nb / 49;
    const int rr  = nb - n * 49;
    const int th  = rr / 7;
    const int tw  = rr - th * 7;
    const int h0  = th * 8 - 1;
    const int w0  = tw * 8 - 1;

    // ---- Phase 1: issue halo loads (400 units of 64B int32 -> 16B int8).
    // unit0 = tid, unit1 = tid+256 (threads 0..143 only).
    const int pix0 = tid >> 2, q0 = tid & 3;
    const int hr0 = pix0 / 10, hc0 = pix0 - hr0 * 10;
    const bool has1 = tid < 144;
    const int pix1 = pix0 + 64;
    const int hr1 = pix1 / 10, hc1 = pix1 - hr1 * 10;

    int4v r00, r01, r02, r03, r10, r11, r12, r13;
    const int gh0 = h0 + hr0, gw0 = w0 + hc0;
    const bool ok0 = ((unsigned)gh0 < 56u) & ((unsigned)gw0 < 56u);
    if (ok0) {
        const int4v* s = (const int4v*)x32 + (((n * 56 + gh0) * 56 + gw0) << 4) + (q0 << 2);
        r00 = s[0]; r01 = s[1]; r02 = s[2]; r03 = s[3];
    }
    bool ok1 = false;
    if (has1) {
        int gh1 = h0 + hr1, gw1 = w0 + hc1;
        ok1 = ((unsigned)gh1 < 56u) & ((unsigned)gw1 < 56u);
        if (ok1) {
            const int4v* s = (const int4v*)x32 + (((n * 56 + gh1) * 56 + gw1) << 4) + (q0 << 2);
            r10 = s[0]; r11 = s[1]; r12 = s[2]; r13 = s[3];
        }
    }
    __builtin_amdgcn_sched_barrier(0);

    // ---- Phase 2: issue depth-4 weight preload (kt = 0..3) while halo loads
    // are in flight. Pinned so the scheduler can't sink these into the loop.
    const char* wb = w8 + (((wv * 2) * 64 + lane) << 4);
    int4v bR[4][2];
#pragma unroll
    for (int i = 0; i < 4; ++i) {
        bR[i][0] = *(const int4v*)(wb);
        bR[i][1] = *(const int4v*)(wb + 1024);
        wb += 8192;
    }
    __builtin_amdgcn_sched_barrier(0);

    // ---- Phase 3: pack + LDS write (waits only on the older halo loads).
    {
        int4v pk = {0, 0, 0, 0};
        if (ok0) { pk.x = pack4(r00); pk.y = pack4(r01); pk.z = pack4(r02); pk.w = pack4(r03); }
        *(int4v*)(hx + pix0 * PIXB + (q0 << 4)) = pk;
    }
    if (has1) {
        int4v pk = {0, 0, 0, 0};
        if (ok1) { pk.x = pack4(r10); pk.y = pack4(r11); pk.z = pack4(r12); pk.w = pack4(r13); }
        *(int4v*)(hx + pix1 * PIXB + (q0 << 4)) = pk;
    }
    __syncthreads();

    // ---- Compute: rolling 4-deep weight prefetch, fully unrolled kt loop.
    const char* ap = hx + ((l15 >> 3) * 10 + (l15 & 7)) * PIXB + (l4 << 4);

    int4v acc[4][2];
#pragma unroll
    for (int mt = 0; mt < 4; ++mt) {
        acc[mt][0] = (int4v){0, 0, 0, 0};
        acc[mt][1] = (int4v){0, 0, 0, 0};
    }

    int toff = 0;
#pragma unroll
    for (int kt = 0; kt < 9; ++kt) {
        int4v c0 = bR[kt & 3][0];
        int4v c1 = bR[kt & 3][1];
        if (kt < 5) {                          // prefetch kt+4
            bR[kt & 3][0] = *(const int4v*)(wb);
            bR[kt & 3][1] = *(const int4v*)(wb + 1024);
            wb += 8192;
        }
#pragma unroll
        for (int mt = 0; mt < 4; ++mt) {
            int4v a = *(const int4v*)(ap + toff + mt * 1600);
            acc[mt][0] = __builtin_amdgcn_mfma_i32_16x16x64_i8(c0, a, acc[mt][0], 0, 0, 0);
            acc[mt][1] = __builtin_amdgcn_mfma_i32_16x16x64_i8(c1, a, acc[mt][1], 0, 0, 0);
        }
        toff += 80;
        if ((kt == 2) | (kt == 5)) toff += 560;
    }

    // ---- Epilogue: lane holds 4 consecutive channels -> dwordx4 stores.
    const int chb = wv * 32 + (l4 << 2);
    int4v bv0 = *(const int4v*)(bias + chb);
    int4v bv1 = *(const int4v*)(bias + chb + 16);
    int* ob = out + (((n * 56 + th * 8) * 56 + tw * 8) << 7);
    const int pc = l15 & 7;
    const int prl = l15 >> 3;
#pragma unroll
    for (int mt = 0; mt < 4; ++mt) {
        int pr = (mt << 1) + prl;
        int* o = ob + ((pr * 56 + pc) << 7) + chb;
        *(int4v*)(o)      = acc[mt][0] + bv0;
        *(int4v*)(o + 16) = acc[mt][1] + bv1;
    }
}

// ---------------------------------------------------------------------------
// Fallback (only if workspace is too small): direct conv, 1 thread/output.
__global__ __launch_bounds__(256) void conv_naive_kernel(const int* __restrict__ x,
                                                         const int* __restrict__ wgt,
                                                         const int* __restrict__ bias,
                                                         int* __restrict__ out) {
    int idx = blockIdx.x * 256 + threadIdx.x;
    if (idx >= N_OUT) return;
    int ch  = idx & 127;
    int pix = idx >> 7;
    int n  = pix / 3136;
    int r2 = pix - n * 3136;
    int h  = r2 / 56;
    int w  = r2 - h * 56;
    int acc = bias[ch];
    for (int kh = 0; kh < 3; ++kh) {
        int hxr = h + kh - 1;
        if ((unsigned)hxr >= 56u) continue;
        for (int kw = 0; kw < 3; ++kw) {
            int wx = w + kw - 1;
            if ((unsigned)wx >= 56u) continue;
            const int* xp = x + ((n * 56 + hxr) * 56 + wx) * 64;
            const int* wp = wgt + ch * KTOT + (kh * 3 + kw) * 64;
            for (int ic = 0; ic < 64; ++ic) acc += xp[ic] * wp[ic];
        }
    }
    out[idx] = acc;
}

// ---------------------------------------------------------------------------
extern "C" void kernel_launch(void* const* d_in, const int* in_sizes, int n_in,
                              void* d_out, int out_size, void* d_ws, size_t ws_size,
                              hipStream_t stream) {
    const int* x    = (const int*)d_in[0];
    const int* wgt  = (const int*)d_in[1];
    const int* bias = (const int*)d_in[2];
    int* out = (int*)d_out;

    if (ws_size >= (size_t)N_W) {
        char* w8 = (char*)d_ws;              // N_W bytes, fragment order
        pack_w_kernel<<<N_W / 4 / 256, 256, 0, stream>>>(wgt, (unsigned int*)w8);
        conv_halo_kernel<<<NTILES, 256, 0, stream>>>(x, w8, bias, out);
    } else {
        conv_naive_kernel<<<(N_OUT + 255) / 256, 256, 0, stream>>>(x, wgt, bias, out);
    }
}